// Round 10
// baseline (1889.879 us; speedup 1.0000x reference)
//
#include <hip/hip_runtime.h>
#include <math.h>

#define Bn 128
#define Tn 512
#define Dn 32
#define Hn 128
#define Gn 512   // 4*H
#define Ln 3

// LDS-only barrier: does NOT drain vmcnt.
#define BAR_LDS() asm volatile("s_waitcnt lgkmcnt(0)\n\ts_barrier" ::: "memory")

typedef _Float16 h2 __attribute__((ext_vector_type(2)));

__device__ __forceinline__ float dot2(h2 a, h2 b, float c) {
    return __builtin_amdgcn_fdot2(a, b, c, false);
}
__device__ __forceinline__ h2 pkh(float a, float b) {
    h2 r; r.x = (_Float16)a; r.y = (_Float16)b; return r;
}
__device__ __forceinline__ float bcastf(float v, int l) {
    return __int_as_float(__builtin_amdgcn_readlane(__float_as_int(v), l));
}
__device__ __forceinline__ float sigm(float x) {
    return __builtin_amdgcn_rcpf(1.f + __expf(-x));
}
__device__ __forceinline__ float tanh_fast(float x) {
    return 1.f - 2.f * __builtin_amdgcn_rcpf(1.f + __expf(2.f * x));
}

#define KEEPH(x) asm volatile("" : "+v"(x))
// 8 packed half2 from 16 consecutive floats at R
#define DECL8(P, R) \
  h2 P##0=pkh(R[0],R[1]),   P##1=pkh(R[2],R[3]),   P##2=pkh(R[4],R[5]),   P##3=pkh(R[6],R[7]), \
     P##4=pkh(R[8],R[9]),   P##5=pkh(R[10],R[11]), P##6=pkh(R[12],R[13]), P##7=pkh(R[14],R[15]);
#define KEEP8(P) \
  KEEPH(P##0); KEEPH(P##1); KEEPH(P##2); KEEPH(P##3); \
  KEEPH(P##4); KEEPH(P##5); KEEPH(P##6); KEEPH(P##7);

// One broadcast pair feeds 8 dot2 (2 units x 4 gates).
#define DOTJ(j) { \
    h2 s = pkh(bcastf(hn, 2*(j)), bcastf(hn, 2*(j)+1)); \
    accAI = dot2(s, wAI##j, accAI); accAF = dot2(s, wAF##j, accAF); \
    accAG = dot2(s, wAG##j, accAG); accAO = dot2(s, wAO##j, accAO); \
    accBI = dot2(s, wBI##j, accBI); accBF = dot2(s, wBF##j, accBF); \
    accBG = dot2(s, wBG##j, accBG); accBO = dot2(s, wBO##j, accBO); }

// ---------------------------------------------------------------------------
// GEMM: pre[M, 512] = A_chunk[M, K] * W[512, K]^T + (b_ih + b_hh)
// ---------------------------------------------------------------------------
__global__ __launch_bounds__(256) void gemm_pre(
    const float* __restrict__ A, int K, int rowStrideB, int t0, int tlog,
    const float* __restrict__ W,
    const float* __restrict__ bi, const float* __restrict__ bh,
    float* __restrict__ C)
{
    __shared__ __align__(16) float As[8][128];
    __shared__ __align__(16) float Bs[8][128];
    const int tid  = threadIdx.x;
    const int row0 = blockIdx.x * 128;
    const int col0 = blockIdx.y * 128;
    const int ty = tid >> 4, tx = tid & 15;
    const int lr = tid >> 1, lk = (tid & 1) * 4;
    const int tmask = (1 << tlog) - 1;

    float acc[8][8];
    #pragma unroll
    for (int i = 0; i < 8; i++)
        #pragma unroll
        for (int j = 0; j < 8; j++) acc[i][j] = 0.f;

    for (int k0 = 0; k0 < K; k0 += 8) {
        {
            int rg = row0 + lr;
            int b_idx = rg >> tlog;
            int tt = rg & tmask;
            const float* ap = A + (size_t)b_idx * rowStrideB +
                              (size_t)(t0 + tt) * K + (k0 + lk);
            float4 av = *(const float4*)ap;
            As[lk + 0][lr] = av.x; As[lk + 1][lr] = av.y;
            As[lk + 2][lr] = av.z; As[lk + 3][lr] = av.w;
            const float* wp = W + (size_t)(col0 + lr) * K + (k0 + lk);
            float4 wv = *(const float4*)wp;
            Bs[lk + 0][lr] = wv.x; Bs[lk + 1][lr] = wv.y;
            Bs[lk + 2][lr] = wv.z; Bs[lk + 3][lr] = wv.w;
        }
        __syncthreads();
        #pragma unroll
        for (int kk = 0; kk < 8; kk++) {
            float4 a0 = *(const float4*)&As[kk][ty * 8];
            float4 a1 = *(const float4*)&As[kk][ty * 8 + 4];
            float4 b0 = *(const float4*)&Bs[kk][tx * 8];
            float4 b1v = *(const float4*)&Bs[kk][tx * 8 + 4];
            float av[8] = {a0.x, a0.y, a0.z, a0.w, a1.x, a1.y, a1.z, a1.w};
            float bv[8] = {b0.x, b0.y, b0.z, b0.w, b1v.x, b1v.y, b1v.z, b1v.w};
            #pragma unroll
            for (int i = 0; i < 8; i++)
                #pragma unroll
                for (int j = 0; j < 8; j++) acc[i][j] += av[i] * bv[j];
        }
        __syncthreads();
    }
    #pragma unroll
    for (int i = 0; i < 8; i++) {
        int r = row0 + ty * 8 + i;
        #pragma unroll
        for (int j = 0; j < 8; j += 4) {
            int g = col0 + tx * 8 + j;
            float4 o;
            o.x = acc[i][j + 0] + bi[g + 0] + bh[g + 0];
            o.y = acc[i][j + 1] + bi[g + 1] + bh[g + 1];
            o.z = acc[i][j + 2] + bi[g + 2] + bh[g + 2];
            o.w = acc[i][j + 3] + bi[g + 3] + bh[g + 3];
            *(float4*)&C[(size_t)r * Gn + g] = o;
        }
    }
}

// ---------------------------------------------------------------------------
// LSTM scan v6. 512 threads (8 waves), one block per batch item.
// Wave w owns k-window [16w,16w+16). Lane l computes partials for units
// uA=l, uB=64+l (4 gates each, 8 half2 weights/gate, fdot2). ONE barrier
// per step: psum[2][8][128] float4 (double-buffered). Update lanes l<16 of
// wave w own units 16w+l: reduce 8 windows, activate, carry c & h IN
// REGISTERS. Next step's broadcast pairs come from v_readlane of the same
// wave's update lanes -- the recurrent state never touches LDS.
// ---------------------------------------------------------------------------
__global__ __launch_bounds__(512)
__attribute__((amdgpu_waves_per_eu(2, 2)))
void lstm_scan(
    const float* __restrict__ pre,     // [B*TCH, 512]
    const float* __restrict__ w_hh,    // [512, 128] (this layer)
    float* __restrict__ hs,            // [B, T, H] layer output (fp32)
    float* __restrict__ h_state, float* __restrict__ c_state,
    int t0, int TCH, int first)
{
    const int b  = blockIdx.x;
    const int tid = threadIdx.x;
    const int w  = tid >> 6;           // k-window / wave id
    const int l  = tid & 63;
    const int uA = l, uB = 64 + l;     // dot-coverage units
    const int k0 = 16 * w;             // this wave's k-window start
    const bool upd = (l < 16);
    const int u = 16 * w + (l & 15);   // update unit (valid when upd)

    __shared__ __align__(16) float4 psum[2][8][Hn];   // 32 KB

    // --- weights: 2 units x 4 gates x 16 k = 64 half2, pinned ---
    const float* rAI = w_hh + (size_t)(0 * Hn + uA) * Hn + k0;
    const float* rAF = w_hh + (size_t)(1 * Hn + uA) * Hn + k0;
    const float* rAG = w_hh + (size_t)(2 * Hn + uA) * Hn + k0;
    const float* rAO = w_hh + (size_t)(3 * Hn + uA) * Hn + k0;
    const float* rBI = w_hh + (size_t)(0 * Hn + uB) * Hn + k0;
    const float* rBF = w_hh + (size_t)(1 * Hn + uB) * Hn + k0;
    const float* rBG = w_hh + (size_t)(2 * Hn + uB) * Hn + k0;
    const float* rBO = w_hh + (size_t)(3 * Hn + uB) * Hn + k0;
    DECL8(wAI, rAI) DECL8(wAF, rAF) DECL8(wAG, rAG) DECL8(wAO, rAO)
    DECL8(wBI, rBI) DECL8(wBF, rBF) DECL8(wBG, rBG) DECL8(wBO, rBO)
    KEEP8(wAI) KEEP8(wAF) KEEP8(wAG) KEEP8(wAO)
    KEEP8(wBI) KEEP8(wBF) KEEP8(wBG) KEEP8(wBO)

    float hn = 0.f, cr = 0.f;
    if (!first && upd) {
        hn = h_state[b * Hn + u];
        cr = c_state[b * Hn + u];
    }

    // pre: update lanes read pre[t][g*128+u]
    const float* pb = pre + (size_t)b * TCH * Gn + u;
    float* hsb = hs + ((size_t)b * Tn + t0) * Hn;

    float pI0 = 0.f, pF0 = 0.f, pG0 = 0.f, pO0 = 0.f;
    float pI1 = 0.f, pF1 = 0.f, pG1 = 0.f, pO1 = 0.f;
    if (upd) {
        pI0 = pb[0]; pF0 = pb[128]; pG0 = pb[256]; pO0 = pb[384];
        if (TCH > 1) {
            pI1 = pb[Gn + 0]; pF1 = pb[Gn + 128];
            pG1 = pb[Gn + 256]; pO1 = pb[Gn + 384];
        } else { pI1 = pI0; pF1 = pF0; pG1 = pG0; pO1 = pO0; }
    }

    for (int t = 0; t < TCH; t++) {
        const int buf = t & 1;

        // prefetch pre[t+2] (stays in flight across the barrier)
        float nI = 0.f, nF = 0.f, nG = 0.f, nO = 0.f;
        if (upd) {
            int tn = (t + 2 < TCH) ? (t + 2) : (TCH - 1);
            const float* p = pb + (size_t)tn * Gn;
            nI = p[0]; nF = p[128]; nG = p[256]; nO = p[384];
        }

        // dot phase: h broadcast via readlane of this wave's update lanes
        float accAI = 0.f, accAF = 0.f, accAG = 0.f, accAO = 0.f;
        float accBI = 0.f, accBF = 0.f, accBG = 0.f, accBO = 0.f;
        DOTJ(0) DOTJ(1) DOTJ(2) DOTJ(3)
        DOTJ(4) DOTJ(5) DOTJ(6) DOTJ(7)

        psum[buf][w][uA] = make_float4(accAI, accAF, accAG, accAO);
        psum[buf][w][uB] = make_float4(accBI, accBF, accBG, accBO);
        BAR_LDS();

        if (upd) {
            float4 s0 = psum[buf][0][u], s1 = psum[buf][1][u];
            float4 s2 = psum[buf][2][u], s3 = psum[buf][3][u];
            float4 s4 = psum[buf][4][u], s5 = psum[buf][5][u];
            float4 s6 = psum[buf][6][u], s7 = psum[buf][7][u];
            float gi = (((s0.x + s1.x) + (s2.x + s3.x)) +
                        ((s4.x + s5.x) + (s6.x + s7.x))) + pI0;
            float gf = (((s0.y + s1.y) + (s2.y + s3.y)) +
                        ((s4.y + s5.y) + (s6.y + s7.y))) + pF0;
            float gg = (((s0.z + s1.z) + (s2.z + s3.z)) +
                        ((s4.z + s5.z) + (s6.z + s7.z))) + pG0;
            float go = (((s0.w + s1.w) + (s2.w + s3.w)) +
                        ((s4.w + s5.w) + (s6.w + s7.w))) + pO0;
            float iv = sigm(gi);
            float fv = sigm(gf);
            float gv = tanh_fast(gg);
            float ov = sigm(go);
            cr = fv * cr + iv * gv;
            hn = ov * tanh_fast(cr);
            hsb[(size_t)t * Hn + u] = hn;     // store stays in flight
        }

        pI0 = pI1; pF0 = pF1; pG0 = pG1; pO0 = pO1;
        pI1 = nI;  pF1 = nF;  pG1 = nG;  pO1 = nO;
    }

    if (upd) {
        h_state[b * Hn + u] = hn;
        c_state[b * Hn + u] = cr;
    }
}

// ---------------------------------------------------------------------------
// Attention pooling + MLP head. One block per batch item, 256 threads.
// ---------------------------------------------------------------------------
__global__ __launch_bounds__(256) void head_kernel(
    const float* __restrict__ hs,
    const float* __restrict__ w_attn, const float* __restrict__ b_attn,
    const float* __restrict__ w1, const float* __restrict__ b1,
    const float* __restrict__ w2, const float* __restrict__ b2,
    float* __restrict__ out)
{
    const int b = blockIdx.x;
    const int tid = threadIdx.x;
    __shared__ __align__(16) float wa_sh[Hn];
    __shared__ __align__(16) float sc[Tn];
    __shared__ __align__(16) float red[256];
    __shared__ __align__(16) float ctx_sh[Hn];
    __shared__ __align__(16) float h1_sh[64];

    if (tid < Hn) wa_sh[tid] = w_attn[tid];
    __syncthreads();

    const float* hb = hs + (size_t)b * Tn * Hn;

    for (int t = tid; t < Tn; t += 256) {
        const float4* hv = (const float4*)(hb + (size_t)t * Hn);
        const float4* wvv = (const float4*)wa_sh;
        float s = 0.f;
        #pragma unroll
        for (int k = 0; k < 32; k++) {
            float4 h4 = hv[k], w4 = wvv[k];
            s += h4.x * w4.x + h4.y * w4.y + h4.z * w4.z + h4.w * w4.w;
        }
        sc[t] = s + b_attn[0];
    }
    __syncthreads();

    float m = fmaxf(sc[tid], sc[tid + 256]);
    red[tid] = m; __syncthreads();
    for (int s_ = 128; s_ > 0; s_ >>= 1) {
        if (tid < s_) red[tid] = fmaxf(red[tid], red[tid + s_]);
        __syncthreads();
    }
    float mx = red[0];
    __syncthreads();
    float e0 = __expf(sc[tid] - mx), e1 = __expf(sc[tid + 256] - mx);
    sc[tid] = e0; sc[tid + 256] = e1;
    red[tid] = e0 + e1; __syncthreads();
    for (int s_ = 128; s_ > 0; s_ >>= 1) {
        if (tid < s_) red[tid] += red[tid + s_];
        __syncthreads();
    }
    float inv = 1.f / red[0];
    __syncthreads();

    {
        int jj = tid & 127, half = tid >> 7;
        float a = 0.f;
        for (int t = half * 256; t < half * 256 + 256; t++)
            a += sc[t] * hb[(size_t)t * Hn + jj];
        red[tid] = a;
        __syncthreads();
        if (tid < Hn) ctx_sh[tid] = (red[tid] + red[tid + Hn]) * inv;
        __syncthreads();
    }

    if (tid < 64) {
        const float4* wvv = (const float4*)(w1 + (size_t)tid * Hn);
        const float4* cv = (const float4*)ctx_sh;
        float s = 0.f;
        #pragma unroll
        for (int k = 0; k < 32; k++) {
            float4 a = wvv[k], c = cv[k];
            s += a.x * c.x + a.y * c.y + a.z * c.z + a.w * c.w;
        }
        h1_sh[tid] = fmaxf(s + b1[tid], 0.f);
    }
    __syncthreads();

    if (tid < 4) {
        float s = 0.f;
        const float* wvv = w2 + tid * 64;
        #pragma unroll
        for (int k = 0; k < 64; k++) s += wvv[k] * h1_sh[k];
        out[b * 4 + tid] = s + b2[tid];
    }
}

// ---------------------------------------------------------------------------
extern "C" void kernel_launch(void* const* d_in, const int* in_sizes, int n_in,
                              void* d_out, int out_size, void* d_ws, size_t ws_size,
                              hipStream_t stream)
{
    const float* x        = (const float*)d_in[0];
    const float* w_ih0    = (const float*)d_in[1];
    const float* w_ih_rest= (const float*)d_in[2];
    const float* w_hh     = (const float*)d_in[3];
    const float* b_ih     = (const float*)d_in[4];
    const float* b_hh     = (const float*)d_in[5];
    const float* w_attn   = (const float*)d_in[6];
    const float* b_attn   = (const float*)d_in[7];
    const float* w1       = (const float*)d_in[8];
    const float* b1       = (const float*)d_in[9];
    const float* w2       = (const float*)d_in[10];
    const float* b2       = (const float*)d_in[11];
    float* out = (float*)d_out;

    float* ws   = (float*)d_ws;
    float* hs   = ws;
    float* h_st = hs + (size_t)Bn * Tn * Hn;
    float* c_st = h_st + (size_t)Bn * Hn;
    float* pre  = c_st + (size_t)Bn * Hn;

    int tch = 512;
    while (tch > 16) {
        size_t need = ((size_t)Bn * Tn * Hn + 2 * (size_t)Bn * Hn +
                       (size_t)Bn * tch * Gn) * sizeof(float);
        if (need <= ws_size) break;
        tch >>= 1;
    }
    int tlog = 31 - __builtin_clz((unsigned)tch);

    for (int l = 0; l < Ln; l++) {
        const float* A = (l == 0) ? x : hs;
        int K = (l == 0) ? Dn : Hn;
        const float* W = (l == 0) ? w_ih0 : (w_ih_rest + (size_t)(l - 1) * Gn * Hn);
        const float* whl = w_hh + (size_t)l * Gn * Hn;
        for (int c = 0; c < Tn / tch; c++) {
            dim3 gg(tch, 4);
            gemm_pre<<<gg, 256, 0, stream>>>(A, K, Tn * K, c * tch, tlog,
                                             W, b_ih + l * Gn, b_hh + l * Gn, pre);
            lstm_scan<<<Bn, 512, 0, stream>>>(pre, whl, hs, h_st, c_st,
                                              c * tch, tch, c == 0 ? 1 : 0);
        }
    }
    head_kernel<<<Bn, 256, 0, stream>>>(hs, w_attn, b_attn, w1, b1, w2, b2, out);
}